// Round 3
// 4572.810 us; speedup vs baseline: 1.3536x; 1.3536x over previous
//
#include <hip/hip_runtime.h>
#include <math.h>

// JordanRNN B=128,T=2048,I=128,H=256,O=64.
// 32 WGs x 256 thr (4 waves): 8 batch-columns x 4 hidden-quarters. Weights
// register-resident fp16 (unified VGPR/AGPR file; amdgpu_waves_per_eu(1,1) +
// flat_work_group_size pins 1 wave/EU -> no spills; R6-verified).
// R10: FUSED SELF-VALIDATING PACKETS over the PROVEN sc1/MALL transport
// (no sc0, no modes, no coherence self-tests -- R8/R9's sc0 experiments are
// abandoned after two container failures).
// Each lane publishes its h(t-1) u64 slice as a 16B packet {data u64,
// epoch u32, pad} with ONE global_store_dwordx4 sc1: a single aligned 16B
// access is one MALL transaction, so epoch-fresh => data-fresh. This
// deletes R7's ack->flag->poll->load chain (~2-3 serialized MALL RTs/step):
//  - producer: fire-and-forget packet stores at step top (publish BEFORE
//    validate -> no circular wait, deadlock-free by construction)
//  - consumer: PRE-ISSUES its 3 partner packet loads at step top (before
//    the publish store, so s_waitcnt vmcnt(1) after phase A waits ONLY the
//    loads, not the store ack), overlaps the MALL RT with phase A MFMAs,
//    validates embedded epochs, retries only on real skew (monotone epochs
//    + parity ping-pong + mutual per-step validation bound skew to 1 step
//    -- same safety argument as R7's flag protocol).
// ws: pay[2 parity][8 col][4 q][4 wv][64 lanes]x16B = 262144 B. memset 0:
// epoch 0 + data 0 == "h(0)=0 published" for both parities.

#define TSTEPS 2048
#define ISZ 128

typedef _Float16 half8 __attribute__((ext_vector_type(8)));
typedef float f32x4 __attribute__((ext_vector_type(4)));
typedef unsigned int u32;
typedef unsigned int u32x4 __attribute__((ext_vector_type(4)));
typedef unsigned long long u64;

__device__ __forceinline__ f32x4 mfma16(half8 a, half8 b, f32x4 c) {
  return __builtin_amdgcn_mfma_f32_16x16x32_f16(a, b, c, 0, 0, 0);
}
__device__ __forceinline__ float sigm(float x) {
  return __builtin_amdgcn_rcpf(1.f + __expf(-x));
}
__device__ __forceinline__ float tanh_fast(float x) {
  return 1.f - 2.f * __builtin_amdgcn_rcpf(1.f + __expf(2.f * x));
}

// ---- MALL packet ops (sc1 = device-coherent, bypasses non-coherent L2s;
//      same transport class as R7's proven __hip_atomic AGENT ops)
__device__ __forceinline__ void st_pkt(void* p, u32x4 v) {
  asm volatile("global_store_dwordx4 %0, %1, off sc1" :: "v"(p), "v"(v) : "memory");
}
__device__ __forceinline__ void ld_pkt3_issue(const void* p1, const void* p2,
                                              const void* p3, u32x4& r1, u32x4& r2,
                                              u32x4& r3) {
  asm volatile("global_load_dwordx4 %0, %3, off sc1\n\t"
               "global_load_dwordx4 %1, %4, off sc1\n\t"
               "global_load_dwordx4 %2, %5, off sc1"
               : "=&v"(r1), "=&v"(r2), "=&v"(r3)
               : "v"(p1), "v"(p2), "v"(p3) : "memory");
}
__device__ __forceinline__ void ld_pkt3_wait(const void* p1, const void* p2,
                                             const void* p3, u32x4& r1, u32x4& r2,
                                             u32x4& r3) {
  asm volatile("global_load_dwordx4 %0, %3, off sc1\n\t"
               "global_load_dwordx4 %1, %4, off sc1\n\t"
               "global_load_dwordx4 %2, %5, off sc1\n\t"
               "s_waitcnt vmcnt(0)"
               : "=&v"(r1), "=&v"(r2), "=&v"(r3)
               : "v"(p1), "v"(p2), "v"(p3) : "memory");
}

__global__ __attribute__((amdgpu_flat_work_group_size(256, 256),
                          amdgpu_waves_per_eu(1, 1)))
void jordan_rnn(const float* __restrict__ xg, const float* __restrict__ w_ih,
                const float* __restrict__ w_hh, const float* __restrict__ b_ih,
                const float* __restrict__ b_hh, const float* __restrict__ fc_w,
                const float* __restrict__ fc_b, float* __restrict__ out,
                unsigned char* __restrict__ ws)
{
  const int tid  = threadIdx.x;
  const int lane = tid & 63;
  const int wv   = tid >> 6;          // wave 0..3
  const int n    = lane & 15;
  const int quad = lane >> 4;
  const int col  = blockIdx.x & 7;    // batch column
  const int q    = blockIdx.x >> 3;   // hidden quarter 0..3
  const int u0   = q * 64 + wv * 16;  // this wave's unit slice
  const int b0   = col * 16;

  unsigned char* pay = ws;

  // act cols: 0..127 = x, 128..191 = y(t-1), 192..447 = h
  __shared__ _Float16 act[16][456];
  {
    unsigned int* za = (unsigned int*)&act[0][0];
    for (int i = tid; i < 3648; i += 256) za[i] = 0u;
  }

  // ---- register-resident weights (fp16 B-fragments: lane holds W[n][k32+quad*8+j])
  half8 wr[14], wz[14], win[6], whn[8], wfc[8];
  {
    const int kq = quad * 8;
    const int ur = u0 + n, uz = 256 + u0 + n, un = 512 + u0 + n;
#pragma unroll
    for (int kk = 0; kk < 6; ++kk) {            // k 0..191: w_ih (x|y)
      const float* pr = w_ih + ur * 192 + kk * 32 + kq;
      const float* pz = w_ih + uz * 192 + kk * 32 + kq;
      const float* pn = w_ih + un * 192 + kk * 32 + kq;
#pragma unroll
      for (int j = 0; j < 8; ++j) {
        wr[kk][j] = (_Float16)pr[j]; wz[kk][j] = (_Float16)pz[j]; win[kk][j] = (_Float16)pn[j];
      }
    }
#pragma unroll
    for (int kk = 0; kk < 8; ++kk) {            // k 192..447: w_hh
      const float* pr = w_hh + ur * 256 + kk * 32 + kq;
      const float* pz = w_hh + uz * 256 + kk * 32 + kq;
      const float* pn = w_hh + un * 256 + kk * 32 + kq;
#pragma unroll
      for (int j = 0; j < 8; ++j) {
        wr[6 + kk][j] = (_Float16)pr[j]; wz[6 + kk][j] = (_Float16)pz[j]; whn[kk][j] = (_Float16)pn[j];
      }
    }
#pragma unroll
    for (int kk = 0; kk < 8; ++kk) {            // fc: rows wv*16+n, all K
      const float* pf = fc_w + (wv * 16 + n) * 256 + kk * 32 + kq;
#pragma unroll
      for (int j = 0; j < 8; ++j) wfc[kk][j] = (_Float16)pf[j];
    }
  }
  const float br   = b_ih[u0 + n] + b_hh[u0 + n];
  const float bz   = b_ih[256 + u0 + n] + b_hh[256 + u0 + n];
  const float bin_ = b_ih[512 + u0 + n];
  const float bhn  = b_hh[512 + u0 + n];
  const float fcb  = fc_b[wv * 16 + n];

  float hprev[4] = {0.f, 0.f, 0.f, 0.f};

  // roles
  const int xr = tid >> 4, xc = tid & 15;       // x stage: row, 8 floats at xc*8
  const int prow = lane >> 2, pc4 = lane & 3;   // publish: lane's u64 of own slice
  const int sblk = tid >> 6, srem = tid & 63;   // partner-quarter stage decode
  const int srow = srem >> 2, sc4 = srem & 3;
  const int ok0 = 6 + 2 * q;                    // own-quarter gate frag idx {ok0,ok0+1}
  const int fk0 = 2 * q;                        // own-quarter fc frag idx {fk0,fk0+1}
  const int q1 = (q + 1) & 3, q2 = (q + 2) & 3, q3 = (q + 3) & 3;

  // packet addresses: [parity 131072][col 16384][(q*4+wv) 1024][lane 16]
  unsigned char* cb0 = pay + (size_t)col * 16384;           // parity 0 col base
  unsigned char* cb1 = cb0 + 131072;                        // parity 1 col base
  const int poff = (q * 4 + wv) * 1024 + lane * 16;         // own publish offset
  const int off1 = (q1 * 4 + sblk) * 1024 + srem * 16;      // partner packet offsets
  const int off2 = (q2 * 4 + sblk) * 1024 + srem * 16;
  const int off3 = (q3 * 4 + sblk) * 1024 + srem * 16;

  const float* xbase = xg + (size_t)(b0 + xr) * TSTEPS * ISZ + xc * 8;
  float4 xv0, xv1;                              // x(t) for step t's phase-B stage

  // stage x(0) (consumed by phase A of step 1); prefetch x(1)
  {
    float4 a = *(const float4*)xbase, b = *(const float4*)(xbase + 4);
    union { _Float16 h[8]; uint4 u; } pk;
    pk.h[0]=(_Float16)a.x; pk.h[1]=(_Float16)a.y; pk.h[2]=(_Float16)a.z; pk.h[3]=(_Float16)a.w;
    pk.h[4]=(_Float16)b.x; pk.h[5]=(_Float16)b.y; pk.h[6]=(_Float16)b.z; pk.h[7]=(_Float16)b.w;
    *(uint4*)&act[xr][xc * 8] = pk.u;
    xv0 = *(const float4*)(xbase + ISZ);
    xv1 = *(const float4*)(xbase + ISZ + 4);
  }
  __syncthreads();

  for (int t = 1; t <= TSTEPS; ++t) {
    const u32 tgt = (u32)(t - 1);
    unsigned char* cb = ((t - 1) & 1) ? cb1 : cb0;

    // ---- pre-issue partner packet loads FIRST (so vmcnt(1) later excludes
    //      the publish store); MALL RT overlaps phase A
    u32x4 r1, r2, r3;
    ld_pkt3_issue(cb + off1, cb + off2, cb + off3, r1, r2, r3);

    // ---- P: publish own h(t-1) slice as self-validating packets (fire&forget)
    {
      u64 v = *(const u64*)&act[prow][192 + u0 + pc4 * 4];
      u32x4 pkt;
      pkt[0] = (u32)v; pkt[1] = (u32)(v >> 32); pkt[2] = tgt; pkt[3] = 0u;
      st_pkt(cb + poff, pkt);
    }

    // ---- A: partner-independent pre-MFMAs (overlap the packet-load RT)
    f32x4 aR = {0,0,0,0}, aZ = {0,0,0,0}, aIN = {0,0,0,0}, aHN = {0,0,0,0};
    f32x4 accy = {0,0,0,0};
#pragma unroll
    for (int kk = 0; kk < 4; ++kk) {            // x gates
      half8 af = *(const half8*)&act[n][kk * 32 + quad * 8];
      aR = mfma16(af, wr[kk], aR);
      aZ = mfma16(af, wz[kk], aZ);
      aIN = mfma16(af, win[kk], aIN);
    }
#pragma unroll
    for (int kk = 0; kk < 2; ++kk) {            // own-quarter h gates
      half8 af = *(const half8*)&act[n][(ok0 + kk) * 32 + quad * 8];
      aR = mfma16(af, wr[ok0 + kk], aR);
      aZ = mfma16(af, wz[ok0 + kk], aZ);
      aHN = mfma16(af, whn[ok0 - 6 + kk], aHN);
    }
#pragma unroll
    for (int kk = 0; kk < 2; ++kk) {            // own-quarter fc (y(t-1) partial)
      half8 af = *(const half8*)&act[n][192 + (fk0 + kk) * 32 + quad * 8];
      accy = mfma16(af, wfc[fk0 + kk], accy);
    }

    // ---- wait the 3 loads only (store still in flight), validate epochs
    __builtin_amdgcn_sched_barrier(0);
    asm volatile("s_waitcnt vmcnt(1)" : "+v"(r1), "+v"(r2), "+v"(r3) :: "memory");
    __builtin_amdgcn_sched_barrier(0);
    {
      int ok = (r1[2] >= tgt) && (r2[2] >= tgt) && (r3[2] >= tgt);
      while (!__all(ok)) {
        ld_pkt3_wait(cb + off1, cb + off2, cb + off3, r1, r2, r3);
        ok = (r1[2] >= tgt) && (r2[2] >= tgt) && (r3[2] >= tgt);
      }
    }
    // ---- stage 3 partner h(t-1) quarters into LDS
    *(u64*)&act[srow][192 + q1 * 64 + sblk * 16 + sc4 * 4] = ((u64)r1[1] << 32) | r1[0];
    *(u64*)&act[srow][192 + q2 * 64 + sblk * 16 + sc4 * 4] = ((u64)r2[1] << 32) | r2[0];
    *(u64*)&act[srow][192 + q3 * 64 + sblk * 16 + sc4 * 4] = ((u64)r3[1] << 32) | r3[0];
    __syncthreads();  // S1: full h(t-1) staged

    // ---- B: partner-h gates + partner fc; y(t-1); x(t) stage; x(t+1) prefetch
#pragma unroll
    for (int kk = 6; kk < 14; ++kk) {
      if (kk == ok0 || kk == ok0 + 1) continue;
      half8 af = *(const half8*)&act[n][kk * 32 + quad * 8];
      aR = mfma16(af, wr[kk], aR);
      aZ = mfma16(af, wz[kk], aZ);
      aHN = mfma16(af, whn[kk - 6], aHN);
    }
#pragma unroll
    for (int kk = 0; kk < 8; ++kk) {
      if (kk == fk0 || kk == fk0 + 1) continue;
      half8 af = *(const half8*)&act[n][192 + kk * 32 + quad * 8];
      accy = mfma16(af, wfc[kk], accy);
    }
    if (t > 1) {
#pragma unroll
      for (int r = 0; r < 4; ++r)
        act[quad * 4 + r][128 + wv * 16 + n] = (_Float16)tanh_fast(accy[r] + fcb);
    }
    // t==1: y(0)=0 already in act
    {
      union { _Float16 h[8]; uint4 u; } pk;
      pk.h[0]=(_Float16)xv0.x; pk.h[1]=(_Float16)xv0.y; pk.h[2]=(_Float16)xv0.z; pk.h[3]=(_Float16)xv0.w;
      pk.h[4]=(_Float16)xv1.x; pk.h[5]=(_Float16)xv1.y; pk.h[6]=(_Float16)xv1.z; pk.h[7]=(_Float16)xv1.w;
      *(uint4*)&act[xr][xc * 8] = pk.u;
      const size_t ts = (t + 1 < TSTEPS) ? (size_t)(t + 1) : (size_t)(TSTEPS - 1);
      xv0 = *(const float4*)(xbase + ts * ISZ);
      xv1 = *(const float4*)(xbase + ts * ISZ + 4);
    }
    __syncthreads();  // S2: y(t-1) + x(t) staged

    // ---- C: y gates K4-5, then gating
#pragma unroll
    for (int kk = 4; kk < 6; ++kk) {
      half8 af = *(const half8*)&act[n][kk * 32 + quad * 8];
      aR = mfma16(af, wr[kk], aR);
      aZ = mfma16(af, wz[kk], aZ);
      aIN = mfma16(af, win[kk], aIN);
    }
#pragma unroll
    for (int r = 0; r < 4; ++r) {
      float rg = sigm(aR[r] + br);
      float zg = sigm(aZ[r] + bz);
      float nn = tanh_fast(aIN[r] + bin_ + rg * (aHN[r] + bhn));
      float hv = (1.f - zg) * nn + zg * hprev[r];
      hprev[r] = hv;
      act[quad * 4 + r][192 + u0 + n] = (_Float16)hv;
    }
    __syncthreads();  // S3: own h(t) quarter complete in act
  }

  // ---- epilogue: publish h(T), exchange, y(T) = tanh(fc h(T) + b)
  {
    const u32 tgt = (u32)TSTEPS;
    unsigned char* cb = (TSTEPS & 1) ? cb1 : cb0;

    u32x4 r1, r2, r3;
    ld_pkt3_issue(cb + off1, cb + off2, cb + off3, r1, r2, r3);
    {
      u64 v = *(const u64*)&act[prow][192 + u0 + pc4 * 4];
      u32x4 pkt;
      pkt[0] = (u32)v; pkt[1] = (u32)(v >> 32); pkt[2] = tgt; pkt[3] = 0u;
      st_pkt(cb + poff, pkt);
    }

    f32x4 accy = {0,0,0,0};
#pragma unroll
    for (int kk = 0; kk < 2; ++kk) {
      half8 af = *(const half8*)&act[n][192 + (fk0 + kk) * 32 + quad * 8];
      accy = mfma16(af, wfc[fk0 + kk], accy);
    }

    __builtin_amdgcn_sched_barrier(0);
    asm volatile("s_waitcnt vmcnt(1)" : "+v"(r1), "+v"(r2), "+v"(r3) :: "memory");
    __builtin_amdgcn_sched_barrier(0);
    {
      int ok = (r1[2] >= tgt) && (r2[2] >= tgt) && (r3[2] >= tgt);
      while (!__all(ok)) {
        ld_pkt3_wait(cb + off1, cb + off2, cb + off3, r1, r2, r3);
        ok = (r1[2] >= tgt) && (r2[2] >= tgt) && (r3[2] >= tgt);
      }
    }
    *(u64*)&act[srow][192 + q1 * 64 + sblk * 16 + sc4 * 4] = ((u64)r1[1] << 32) | r1[0];
    *(u64*)&act[srow][192 + q2 * 64 + sblk * 16 + sc4 * 4] = ((u64)r2[1] << 32) | r2[0];
    *(u64*)&act[srow][192 + q3 * 64 + sblk * 16 + sc4 * 4] = ((u64)r3[1] << 32) | r3[0];
    __syncthreads();

#pragma unroll
    for (int kk = 0; kk < 8; ++kk) {
      if (kk == fk0 || kk == fk0 + 1) continue;
      half8 af = *(const half8*)&act[n][192 + kk * 32 + quad * 8];
      accy = mfma16(af, wfc[kk], accy);
    }
    if (q == 0) {
#pragma unroll
      for (int r = 0; r < 4; ++r)
        out[(size_t)(b0 + quad * 4 + r) * 64 + wv * 16 + n] = tanh_fast(accy[r] + fcb);
    }
  }
}

extern "C" void kernel_launch(void* const* d_in, const int* in_sizes, int n_in,
                              void* d_out, int out_size, void* d_ws, size_t ws_size,
                              hipStream_t stream) {
  hipMemsetAsync(d_ws, 0, 262144, stream);  // both parities: epoch 0 + h(0)=0
  jordan_rnn<<<dim3(32), dim3(256), 0, stream>>>(
      (const float*)d_in[0], (const float*)d_in[1], (const float*)d_in[2],
      (const float*)d_in[3], (const float*)d_in[4], (const float*)d_in[5],
      (const float*)d_in[6], (float*)d_out, (unsigned char*)d_ws);
}

// Round 6
// 4512.442 us; speedup vs baseline: 1.3717x; 1.0134x over previous
//
#include <hip/hip_runtime.h>
#include <math.h>

// JordanRNN B=128,T=2048,I=128,H=256,O=64.
// 32 WGs x 256 thr (4 waves): 8 batch-columns x 4 hidden-quarters. Weights
// register-resident fp16 (unified VGPR/AGPR file; amdgpu_waves_per_eu(1,1) +
// flat_work_group_size pins 1 wave/EU -> no spills; R6-verified).
// R13 = R12 rebench + hang-insurance. R12's design (eager publish + XOR
// tear-proof packets) re-audited: no deadlock path found (acceptance
// ordering: partner's epoch-t+1 overwrite requires partner's step-t+1
// validation -> requires our epoch-t publish -> after our whole-WG S1/S2 ->
// after ALL our waves accepted epoch t-1; tear retries bounded: settled
// stores are XOR-consistent forever after). R11 (riskier variant) ran to
// completion -> structure doesn't wedge; R12's double container failure is
// most plausibly infra (session shows 507s pushes / 154s acquires).
// Hardening this round (all free):
//  (a) s_sleep(1) backoff in retry loops -- no cost when retries are rare,
//      prevents MALL hammering if anything ever spins long.
//  (b) epilogue exchange only for q==0 WGs (the only out-writers); q!=0
//      WGs exit after their final publish (stores complete post-endpgm).
//  (c) publish moved before the phase-C LDS writes (register-sourced).
// Protocol (from R12): packet = {d0, d1, epoch, d0^d1^epoch} stored as one
// global_store_dwordx4 sc1 at end of phase C (the moment h(t) exists in
// registers). Consumer pre-issues 3 partner packet loads at step top,
// overlaps the MALL RT with phase A MFMAs, validates epoch>=tgt AND XOR
// (accepts no torn visibility at any >=4B granularity; dwords are atomic).
// Memset zeros are XOR-valid = "epoch 0, h(0)=0". Parity ping-pong bounds
// skew to 1 step. Deadlock-free: publish is unconditional fire-and-forget.
// ws: pay[2 parity][8 col][16 slots][64 lanes]x16B = 262144 B.

#define TSTEPS 2048
#define ISZ 128

typedef _Float16 half8 __attribute__((ext_vector_type(8)));
typedef float f32x4 __attribute__((ext_vector_type(4)));
typedef unsigned int u32;
typedef unsigned int u32x4 __attribute__((ext_vector_type(4)));
typedef unsigned long long u64;

__device__ __forceinline__ f32x4 mfma16(half8 a, half8 b, f32x4 c) {
  return __builtin_amdgcn_mfma_f32_16x16x32_f16(a, b, c, 0, 0, 0);
}
__device__ __forceinline__ float sigm(float x) {
  return __builtin_amdgcn_rcpf(1.f + __expf(-x));
}
__device__ __forceinline__ float tanh_fast(float x) {
  return 1.f - 2.f * __builtin_amdgcn_rcpf(1.f + __expf(2.f * x));
}

// ---- MALL packet ops (sc1 = device-coherent, bypasses non-coherent L2s)
__device__ __forceinline__ void st_pkt(void* p, u32x4 v) {
  asm volatile("global_store_dwordx4 %0, %1, off sc1" :: "v"(p), "v"(v) : "memory");
}
__device__ __forceinline__ void ld_pkt3_issue(const void* p1, const void* p2,
                                              const void* p3, u32x4& r1, u32x4& r2,
                                              u32x4& r3) {
  asm volatile("global_load_dwordx4 %0, %3, off sc1\n\t"
               "global_load_dwordx4 %1, %4, off sc1\n\t"
               "global_load_dwordx4 %2, %5, off sc1"
               : "=&v"(r1), "=&v"(r2), "=&v"(r3)
               : "v"(p1), "v"(p2), "v"(p3) : "memory");
}
__device__ __forceinline__ void ld_pkt3_wait(const void* p1, const void* p2,
                                             const void* p3, u32x4& r1, u32x4& r2,
                                             u32x4& r3) {
  asm volatile("global_load_dwordx4 %0, %3, off sc1\n\t"
               "global_load_dwordx4 %1, %4, off sc1\n\t"
               "global_load_dwordx4 %2, %5, off sc1\n\t"
               "s_waitcnt vmcnt(0)"
               : "=&v"(r1), "=&v"(r2), "=&v"(r3)
               : "v"(p1), "v"(p2), "v"(p3) : "memory");
}
// packet validity: epoch fresh AND XOR-consistent (tear-proof)
#define PKT_OK(r, tgt) (((r)[2] >= (tgt)) && (((r)[0] ^ (r)[1] ^ (r)[2]) == (r)[3]))

__global__ __attribute__((amdgpu_flat_work_group_size(256, 256),
                          amdgpu_waves_per_eu(1, 1)))
void jordan_rnn(const float* __restrict__ xg, const float* __restrict__ w_ih,
                const float* __restrict__ w_hh, const float* __restrict__ b_ih,
                const float* __restrict__ b_hh, const float* __restrict__ fc_w,
                const float* __restrict__ fc_b, float* __restrict__ out,
                unsigned char* __restrict__ ws)
{
  const int tid  = threadIdx.x;
  const int lane = tid & 63;
  const int wv   = tid >> 6;          // wave 0..3
  const int n    = lane & 15;
  const int quad = lane >> 4;
  const int col  = blockIdx.x & 7;    // batch column
  const int q    = blockIdx.x >> 3;   // hidden quarter 0..3
  const int u0   = q * 64 + wv * 16;  // this wave's unit slice
  const int b0   = col * 16;

  unsigned char* pay = ws;

  // act cols: 0..127 = x, 128..191 = y(t-1), 192..447 = h
  __shared__ _Float16 act[16][456];
  {
    unsigned int* za = (unsigned int*)&act[0][0];
    for (int i = tid; i < 3648; i += 256) za[i] = 0u;
  }

  // ---- register-resident weights (fp16 B-fragments: lane holds W[n][k32+quad*8+j])
  half8 wr[14], wz[14], win[6], whn[8], wfc[8];
  {
    const int kq = quad * 8;
    const int ur = u0 + n, uz = 256 + u0 + n, un = 512 + u0 + n;
#pragma unroll
    for (int kk = 0; kk < 6; ++kk) {            // k 0..191: w_ih (x|y)
      const float* pr = w_ih + ur * 192 + kk * 32 + kq;
      const float* pz = w_ih + uz * 192 + kk * 32 + kq;
      const float* pn = w_ih + un * 192 + kk * 32 + kq;
#pragma unroll
      for (int j = 0; j < 8; ++j) {
        wr[kk][j] = (_Float16)pr[j]; wz[kk][j] = (_Float16)pz[j]; win[kk][j] = (_Float16)pn[j];
      }
    }
#pragma unroll
    for (int kk = 0; kk < 8; ++kk) {            // k 192..447: w_hh
      const float* pr = w_hh + ur * 256 + kk * 32 + kq;
      const float* pz = w_hh + uz * 256 + kk * 32 + kq;
      const float* pn = w_hh + un * 256 + kk * 32 + kq;
#pragma unroll
      for (int j = 0; j < 8; ++j) {
        wr[6 + kk][j] = (_Float16)pr[j]; wz[6 + kk][j] = (_Float16)pz[j]; whn[kk][j] = (_Float16)pn[j];
      }
    }
#pragma unroll
    for (int kk = 0; kk < 8; ++kk) {            // fc: rows wv*16+n, all K
      const float* pf = fc_w + (wv * 16 + n) * 256 + kk * 32 + kq;
#pragma unroll
      for (int j = 0; j < 8; ++j) wfc[kk][j] = (_Float16)pf[j];
    }
  }
  const float br   = b_ih[u0 + n] + b_hh[u0 + n];
  const float bz   = b_ih[256 + u0 + n] + b_hh[256 + u0 + n];
  const float bin_ = b_ih[512 + u0 + n];
  const float bhn  = b_hh[512 + u0 + n];
  const float fcb  = fc_b[wv * 16 + n];

  float hprev[4] = {0.f, 0.f, 0.f, 0.f};

  // roles
  const int xr = tid >> 4, xc = tid & 15;       // x stage: row, 8 floats at xc*8
  const int sblk = tid >> 6, srem = tid & 63;   // partner-quarter stage decode
  const int cr = (srem >> 4) * 4;               // column-packet: base row
  const int cc = srem & 15;                     //   col within producer wave slice
  const int ok0 = 6 + 2 * q;                    // own-quarter gate frag idx {ok0,ok0+1}
  const int fk0 = 2 * q;                        // own-quarter fc frag idx {fk0,fk0+1}
  const int q1 = (q + 1) & 3, q2 = (q + 2) & 3, q3 = (q + 3) & 3;

  // packet addresses: [parity 131072][col 16384][(q*4+wv) 1024][lane 16]
  unsigned char* cb0 = pay + (size_t)col * 16384;           // parity 0 col base
  unsigned char* cb1 = cb0 + 131072;                        // parity 1 col base
  const int poff = (q * 4 + wv) * 1024 + lane * 16;         // own publish offset
  const int off1 = (q1 * 4 + sblk) * 1024 + srem * 16;      // partner packet offsets
  const int off2 = (q2 * 4 + sblk) * 1024 + srem * 16;
  const int off3 = (q3 * 4 + sblk) * 1024 + srem * 16;

  const float* xbase = xg + (size_t)(b0 + xr) * TSTEPS * ISZ + xc * 8;
  float4 xv0, xv1;                              // x(t) for step t's phase-B stage

  // stage x(0) (consumed by phase A of step 1); prefetch x(1)
  {
    float4 a = *(const float4*)xbase, b = *(const float4*)(xbase + 4);
    union { _Float16 h[8]; uint4 u; } pk;
    pk.h[0]=(_Float16)a.x; pk.h[1]=(_Float16)a.y; pk.h[2]=(_Float16)a.z; pk.h[3]=(_Float16)a.w;
    pk.h[4]=(_Float16)b.x; pk.h[5]=(_Float16)b.y; pk.h[6]=(_Float16)b.z; pk.h[7]=(_Float16)b.w;
    *(uint4*)&act[xr][xc * 8] = pk.u;
    xv0 = *(const float4*)(xbase + ISZ);
    xv1 = *(const float4*)(xbase + ISZ + 4);
  }
  __syncthreads();

  for (int t = 1; t <= TSTEPS; ++t) {
    const u32 tgt = (u32)(t - 1);
    unsigned char* cb = ((t - 1) & 1) ? cb1 : cb0;   // read parity (t-1)&1

    // ---- pre-issue partner packet loads (MALL RT overlaps phase A); the
    //      matching stores were fired in partners' phase C of step t-1.
    u32x4 r1, r2, r3;
    ld_pkt3_issue(cb + off1, cb + off2, cb + off3, r1, r2, r3);

    // ---- A: partner-independent pre-MFMAs (overlap the packet-load RT)
    f32x4 aR = {0,0,0,0}, aZ = {0,0,0,0}, aIN = {0,0,0,0}, aHN = {0,0,0,0};
    f32x4 accy = {0,0,0,0};
#pragma unroll
    for (int kk = 0; kk < 4; ++kk) {            // x gates
      half8 af = *(const half8*)&act[n][kk * 32 + quad * 8];
      aR = mfma16(af, wr[kk], aR);
      aZ = mfma16(af, wz[kk], aZ);
      aIN = mfma16(af, win[kk], aIN);
    }
#pragma unroll
    for (int kk = 0; kk < 2; ++kk) {            // own-quarter h gates
      half8 af = *(const half8*)&act[n][(ok0 + kk) * 32 + quad * 8];
      aR = mfma16(af, wr[ok0 + kk], aR);
      aZ = mfma16(af, wz[ok0 + kk], aZ);
      aHN = mfma16(af, whn[ok0 - 6 + kk], aHN);
    }
#pragma unroll
    for (int kk = 0; kk < 2; ++kk) {            // own-quarter fc (y(t-1) partial)
      half8 af = *(const half8*)&act[n][192 + (fk0 + kk) * 32 + quad * 8];
      accy = mfma16(af, wfc[fk0 + kk], accy);
    }

    // ---- wait loads, validate epochs + XOR (tear-proof)
    __builtin_amdgcn_sched_barrier(0);
    asm volatile("s_waitcnt vmcnt(0)" : "+v"(r1), "+v"(r2), "+v"(r3) :: "memory");
    __builtin_amdgcn_sched_barrier(0);
    {
      int ok = PKT_OK(r1, tgt) && PKT_OK(r2, tgt) && PKT_OK(r3, tgt);
      while (!__all(ok)) {
        __builtin_amdgcn_s_sleep(1);            // gentle backoff (~64cy)
        ld_pkt3_wait(cb + off1, cb + off2, cb + off3, r1, r2, r3);
        ok = PKT_OK(r1, tgt) && PKT_OK(r2, tgt) && PKT_OK(r3, tgt);
      }
    }
    // ---- stage 3 partner h(t-1) quarters into LDS (column-packet layout:
    //      producer lane L published rows (L>>4)*4+0..3 of col L&15)
    {
      union { u64 u; _Float16 h[4]; } w1, w2, w3;
      w1.u = ((u64)r1[1] << 32) | r1[0];
      w2.u = ((u64)r2[1] << 32) | r2[0];
      w3.u = ((u64)r3[1] << 32) | r3[0];
#pragma unroll
      for (int r = 0; r < 4; ++r) {
        act[cr + r][192 + q1 * 64 + sblk * 16 + cc] = w1.h[r];
        act[cr + r][192 + q2 * 64 + sblk * 16 + cc] = w2.h[r];
        act[cr + r][192 + q3 * 64 + sblk * 16 + cc] = w3.h[r];
      }
    }
    __syncthreads();  // S1: full h(t-1) staged

    // ---- B: partner-h gates + partner fc; y(t-1); x(t) stage; x(t+1) prefetch
#pragma unroll
    for (int kk = 6; kk < 14; ++kk) {
      if (kk == ok0 || kk == ok0 + 1) continue;
      half8 af = *(const half8*)&act[n][kk * 32 + quad * 8];
      aR = mfma16(af, wr[kk], aR);
      aZ = mfma16(af, wz[kk], aZ);
      aHN = mfma16(af, whn[kk - 6], aHN);
    }
#pragma unroll
    for (int kk = 0; kk < 8; ++kk) {
      if (kk == fk0 || kk == fk0 + 1) continue;
      half8 af = *(const half8*)&act[n][192 + kk * 32 + quad * 8];
      accy = mfma16(af, wfc[kk], accy);
    }
    if (t > 1) {
#pragma unroll
      for (int r = 0; r < 4; ++r)
        act[quad * 4 + r][128 + wv * 16 + n] = (_Float16)tanh_fast(accy[r] + fcb);
    }
    // t==1: y(0)=0 already in act
    {
      union { _Float16 h[8]; uint4 u; } pk;
      pk.h[0]=(_Float16)xv0.x; pk.h[1]=(_Float16)xv0.y; pk.h[2]=(_Float16)xv0.z; pk.h[3]=(_Float16)xv0.w;
      pk.h[4]=(_Float16)xv1.x; pk.h[5]=(_Float16)xv1.y; pk.h[6]=(_Float16)xv1.z; pk.h[7]=(_Float16)xv1.w;
      *(uint4*)&act[xr][xc * 8] = pk.u;
      const size_t ts = (t + 1 < TSTEPS) ? (size_t)(t + 1) : (size_t)(TSTEPS - 1);
      xv0 = *(const float4*)(xbase + ts * ISZ);
      xv1 = *(const float4*)(xbase + ts * ISZ + 4);
    }
    __syncthreads();  // S2: y(t-1) + x(t) staged

    // ---- C: y gates K4-5, gating, EAGER register publish, own-h LDS write
#pragma unroll
    for (int kk = 4; kk < 6; ++kk) {
      half8 af = *(const half8*)&act[n][kk * 32 + quad * 8];
      aR = mfma16(af, wr[kk], aR);
      aZ = mfma16(af, wz[kk], aZ);
      aIN = mfma16(af, win[kk], aIN);
    }
    {
      union { _Float16 h[4]; u64 u; } ph;
#pragma unroll
      for (int r = 0; r < 4; ++r) {
        float rg = sigm(aR[r] + br);
        float zg = sigm(aZ[r] + bz);
        float nn = tanh_fast(aIN[r] + bin_ + rg * (aHN[r] + bhn));
        float hv = (1.f - zg) * nn + zg * hprev[r];
        hprev[r] = hv;
        ph.h[r] = (_Float16)hv;
      }
      // publish own column segment from REGISTERS first (epoch t, parity
      // t&1, XOR checksum). Fire-and-forget; consumers validate.
      unsigned char* cbw = (t & 1) ? cb1 : cb0;
      u32x4 pkt;
      pkt[0] = (u32)ph.u; pkt[1] = (u32)(ph.u >> 32); pkt[2] = (u32)t;
      pkt[3] = pkt[0] ^ pkt[1] ^ pkt[2];
      st_pkt(cbw + poff, pkt);
      // then own-quarter LDS write for next step's phase A
#pragma unroll
      for (int r = 0; r < 4; ++r)
        act[quad * 4 + r][192 + u0 + n] = ph.h[r];
    }
    __syncthreads();  // S3: own h(t) quarter complete in act
  }

  // ---- epilogue: h(T) packets were published in the last phase C. Only
  //      q==0 WGs produce out; others exit (their stores complete anyway).
  if (q == 0) {
    const u32 tgt = (u32)TSTEPS;
    unsigned char* cb = (TSTEPS & 1) ? cb1 : cb0;   // parity TSTEPS&1

    u32x4 r1, r2, r3;
    ld_pkt3_issue(cb + off1, cb + off2, cb + off3, r1, r2, r3);

    f32x4 accy = {0,0,0,0};
#pragma unroll
    for (int kk = 0; kk < 2; ++kk) {
      half8 af = *(const half8*)&act[n][192 + (fk0 + kk) * 32 + quad * 8];
      accy = mfma16(af, wfc[fk0 + kk], accy);
    }

    __builtin_amdgcn_sched_barrier(0);
    asm volatile("s_waitcnt vmcnt(0)" : "+v"(r1), "+v"(r2), "+v"(r3) :: "memory");
    __builtin_amdgcn_sched_barrier(0);
    {
      int ok = PKT_OK(r1, tgt) && PKT_OK(r2, tgt) && PKT_OK(r3, tgt);
      while (!__all(ok)) {
        __builtin_amdgcn_s_sleep(1);
        ld_pkt3_wait(cb + off1, cb + off2, cb + off3, r1, r2, r3);
        ok = PKT_OK(r1, tgt) && PKT_OK(r2, tgt) && PKT_OK(r3, tgt);
      }
    }
    {
      union { u64 u; _Float16 h[4]; } w1, w2, w3;
      w1.u = ((u64)r1[1] << 32) | r1[0];
      w2.u = ((u64)r2[1] << 32) | r2[0];
      w3.u = ((u64)r3[1] << 32) | r3[0];
#pragma unroll
      for (int r = 0; r < 4; ++r) {
        act[cr + r][192 + q1 * 64 + sblk * 16 + cc] = w1.h[r];
        act[cr + r][192 + q2 * 64 + sblk * 16 + cc] = w2.h[r];
        act[cr + r][192 + q3 * 64 + sblk * 16 + cc] = w3.h[r];
      }
    }
    __syncthreads();

#pragma unroll
    for (int kk = 0; kk < 8; ++kk) {
      if (kk == fk0 || kk == fk0 + 1) continue;
      half8 af = *(const half8*)&act[n][192 + kk * 32 + quad * 8];
      accy = mfma16(af, wfc[kk], accy);
    }
#pragma unroll
    for (int r = 0; r < 4; ++r)
      out[(size_t)(b0 + quad * 4 + r) * 64 + wv * 16 + n] = tanh_fast(accy[r] + fcb);
  }
}

extern "C" void kernel_launch(void* const* d_in, const int* in_sizes, int n_in,
                              void* d_out, int out_size, void* d_ws, size_t ws_size,
                              hipStream_t stream) {
  hipMemsetAsync(d_ws, 0, 262144, stream);  // both parities: epoch 0 + h(0)=0, XOR-valid
  jordan_rnn<<<dim3(32), dim3(256), 0, stream>>>(
      (const float*)d_in[0], (const float*)d_in[1], (const float*)d_in[2],
      (const float*)d_in[3], (const float*)d_in[4], (const float*)d_in[5],
      (const float*)d_in[6], (float*)d_out, (unsigned char*)d_ws);
}